// Round 2
// baseline (483.311 us; speedup 1.0000x reference)
//
#include <hip/hip_runtime.h>
#include <stdint.h>

#define BB 512
#define TT 1024
#define KK 48
#define PF 8

typedef float v2f __attribute__((ext_vector_type(2)));

// mask may arrive as 1-byte bools (raw numpy) or as 4-byte words.
__device__ __forceinline__ int mask_at(const void* m, int idx, bool bytes) {
    return bytes ? (int)(((const uint8_t*)m)[idx] != 0)
                 : (int)(((const int*)m)[idx] != 0);
}

__device__ __forceinline__ float bcast(float v, int lane) {
    return __int_as_float(__builtin_amdgcn_readlane(__float_as_int(v), lane));
}

__device__ __forceinline__ v2f mk2(float x, float y) { v2f r; r.x = x; r.y = y; return r; }

// ------------- forward algorithm, TWO rows per wave -------------------
// R6: single-row waves expose broadcast latency on the serial chain
// (readlane storm ~380cy SGPR-port bound; LDS roundtrip ~240cy latency
// bound — R5 regression). Fix: interleave two independent rows per wave.
// Row A's ds_write+12x uniform ds_read_b128 fly while row B's FMA tree
// issues, and vice versa. FMAs packed (v_pk_fma_f32) -> 24/row-step.
// Both rows run 1024 padded steps; state captured in-flight at t==len
// (mask is prefix), so blocks are perfectly uniform. Renorm schedule
// replicates the old main+tail pattern exactly -> bit-identical floats.
__global__ __launch_bounds__(64, 1) void crf_fwd(
    const float* __restrict__ em, const int* __restrict__ tags,
    const void* __restrict__ mask, const float* __restrict__ trans,
    const float* __restrict__ start, const float* __restrict__ endt,
    float* __restrict__ ws)
{
    __shared__ __align__(16) float plA[64];
    __shared__ __align__(16) float plB[64];

    const int bid = blockIdx.x;
    const int bA = 2 * bid, bB = 2 * bid + 1;
    const int lane = threadIdx.x;
    const bool active = lane < KK;
    const int j = active ? lane : KK - 1;   // clamp for safe loads

    const bool mb = (*(const int*)mask) == 0x01010101;

    // sequence lengths = popcount of prefix masks
    int cntA = 0, cntB = 0;
    for (int t = lane; t < TT; t += 64) {
        cntA += mask_at(mask, bA * TT + t, mb);
        cntB += mask_at(mask, bB * TT + t, mb);
    }
    #pragma unroll
    for (int off = 32; off >= 1; off >>= 1) {
        cntA += __shfl_xor(cntA, off);
        cntB += __shfl_xor(cntB, off);
    }
    const int lenA = __builtin_amdgcn_readfirstlane(cntA);
    const int lenB = __builtin_amdgcn_readfirstlane(cntB);

    // E packed as pairs along k: etr2[i] = (E[2i][j], E[2i+1][j])
    v2f etr2[KK / 2];
    #pragma unroll
    for (int i = 0; i < KK / 2; ++i) {
        float e0 = active ? __expf(trans[(2 * i)     * KK + j]) : 0.0f;
        float e1 = active ? __expf(trans[(2 * i + 1) * KK + j]) : 0.0f;
        v2f t2 = mk2(e0, e1);
        asm volatile("" : "+v"(t2));
        etr2[i] = t2;
    }

    const float* embA = em + (size_t)bA * TT * KK;
    const float* embB = em + (size_t)bB * TT * KK;

    // init: p = exp(S_0 - c), c = S_0[0]
    float s0A = start[j] + embA[j];
    float s0B = start[j] + embB[j];
    float cAc = bcast(s0A, 0);
    float cBc = bcast(s0B, 0);
    float pA = active ? __expf(s0A - cAc) : 0.0f;
    float pB = active ? __expf(s0B - cBc) : 0.0f;

    plA[lane] = pA;
    plB[lane] = pB;
    asm volatile("" ::: "memory");
    float4 rA[12], rB[12];
    const float* plAf = plA;
    const float* plBf = plB;
    #pragma unroll
    for (int i = 0; i < 12; ++i) rA[i] = *(const float4*)(plAf + 4 * i);
    #pragma unroll
    for (int i = 0; i < 12; ++i) rB[i] = *(const float4*)(plBf + 4 * i);
    asm volatile("" ::: "memory");

    // emission prefetch pipelines
    float pipeA[PF], pipeB[PF];
    #pragma unroll
    for (int d = 0; d < PF; ++d) {
        pipeA[d] = embA[(size_t)(1 + d) * KK + j];
        pipeB[d] = embB[(size_t)(1 + d) * KK + j];
    }

    float pcapA = 0.f, pcapB = 0.f, ccapA = 0.f, ccapB = 0.f;

    for (int t = 1; t + PF <= TT + 1; t += PF) {
        // replicate old main/tail renorm split: tail blocks renorm every step
        const bool tailA = (t + PF > lenA);
        const bool tailB = (t + PF > lenB);
        #pragma unroll
        for (int d = 0; d < PF; ++d) {
            const int tc = t + d;
            const bool rn = (d == 0) || (d == 4);
            // capture pre-step state at t == len (final state of the row)
            if (tc == lenA) { pcapA = pA; ccapA = cAc; }
            if (tc == lenB) { pcapB = pB; ccapB = cBc; }
            // ---------------- row A step ----------------
            {
                float eA = __expf(pipeA[d]);
                { int tt = tc + PF; tt = tt < TT ? tt : TT - 1;
                  pipeA[d] = embA[(size_t)tt * KK + j]; }
                const bool renorm = rn || tailA;
                float s0 = rA[0].x;
                float scale = eA;
                if (renorm) scale *= __builtin_amdgcn_rcpf(s0);
                v2f Q01 = mk2(rA[0].x, rA[0].y) * etr2[0];
                v2f Q23 = mk2(rA[0].z, rA[0].w) * etr2[1];
                #pragma unroll
                for (int i = 1; i < 12; ++i) {
                    Q01 = __builtin_elementwise_fma(mk2(rA[i].x, rA[i].y), etr2[2 * i],     Q01);
                    Q23 = __builtin_elementwise_fma(mk2(rA[i].z, rA[i].w), etr2[2 * i + 1], Q23);
                }
                if (renorm) cAc += __logf(s0);
                float qs = (Q01.x + Q01.y) + (Q23.x + Q23.y);
                pA = qs * scale;
                asm volatile("" ::: "memory");
                plA[lane] = pA;
                asm volatile("" ::: "memory");
                #pragma unroll
                for (int i = 0; i < 12; ++i) rA[i] = *(const float4*)(plAf + 4 * i);
                asm volatile("" ::: "memory");   // A reads fly under B compute
            }
            // ---------------- row B step ----------------
            {
                float eB = __expf(pipeB[d]);
                { int tt = tc + PF; tt = tt < TT ? tt : TT - 1;
                  pipeB[d] = embB[(size_t)tt * KK + j]; }
                const bool renorm = rn || tailB;
                float s0 = rB[0].x;
                float scale = eB;
                if (renorm) scale *= __builtin_amdgcn_rcpf(s0);
                v2f Q01 = mk2(rB[0].x, rB[0].y) * etr2[0];
                v2f Q23 = mk2(rB[0].z, rB[0].w) * etr2[1];
                #pragma unroll
                for (int i = 1; i < 12; ++i) {
                    Q01 = __builtin_elementwise_fma(mk2(rB[i].x, rB[i].y), etr2[2 * i],     Q01);
                    Q23 = __builtin_elementwise_fma(mk2(rB[i].z, rB[i].w), etr2[2 * i + 1], Q23);
                }
                if (renorm) cBc += __logf(s0);
                float qs = (Q01.x + Q01.y) + (Q23.x + Q23.y);
                pB = qs * scale;
                asm volatile("" ::: "memory");
                plB[lane] = pB;
                asm volatile("" ::: "memory");
                #pragma unroll
                for (int i = 0; i < 12; ++i) rB[i] = *(const float4*)(plBf + 4 * i);
                asm volatile("" ::: "memory");   // B reads fly under next A compute
            }
        }
    }

    // log_z = c + log(sum_j pcap_j * exp(end_j))
    const float ee = active ? __expf(endt[j]) : 0.0f;
    float vA = pcapA * ee;
    float vB = pcapB * ee;
    #pragma unroll
    for (int off = 32; off >= 1; off >>= 1) {
        vA += __shfl_xor(vA, off);
        vB += __shfl_xor(vB, off);
    }

    // ---- fused gold-path scores (mask is prefix: m[t] == (t < len)) ----
    const int* tgA = tags + bA * TT;
    const int* tgB = tags + bB * TT;
    float sqA = 0.f, sqB = 0.f;
    for (int tt2 = lane; tt2 < TT; tt2 += 64) {
        if (tt2 >= 1 && tt2 < lenA) {
            int tp = tgA[tt2 - 1], tn = tgA[tt2];
            sqA += trans[tp * KK + tn] + embA[(size_t)tt2 * KK + tn];
        }
        if (tt2 >= 1 && tt2 < lenB) {
            int tp = tgB[tt2 - 1], tn = tgB[tt2];
            sqB += trans[tp * KK + tn] + embB[(size_t)tt2 * KK + tn];
        }
    }
    #pragma unroll
    for (int off = 32; off >= 1; off >>= 1) {
        sqA += __shfl_xor(sqA, off);
        sqB += __shfl_xor(sqB, off);
    }

    if (lane == 0) {
        int t0A = tgA[0], t0B = tgB[0];
        ws[bA]      = ccapA + __logf(vA);
        ws[BB + bA] = sqA + start[t0A] + embA[t0A] + endt[tgA[lenA - 1]];
        ws[bB]      = ccapB + __logf(vB);
        ws[BB + bB] = sqB + start[t0B] + embB[t0B] + endt[tgB[lenB - 1]];
    }
}

// ---------------- final mean reduction ----------------
__global__ __launch_bounds__(256) void crf_final(const float* __restrict__ ws,
                                                 float* __restrict__ out)
{
    __shared__ float red[256];
    float s = 0.f;
    for (int b = threadIdx.x; b < BB; b += 256) s += ws[b] - ws[BB + b];
    red[threadIdx.x] = s;
    __syncthreads();
    for (int off = 128; off > 0; off >>= 1) {
        if (threadIdx.x < off) red[threadIdx.x] += red[threadIdx.x + off];
        __syncthreads();
    }
    if (threadIdx.x == 0) out[0] = red[0] / (float)BB;
}

extern "C" void kernel_launch(void* const* d_in, const int* in_sizes, int n_in,
                              void* d_out, int out_size, void* d_ws, size_t ws_size,
                              hipStream_t stream) {
    const float* em    = (const float*)d_in[0];
    const int*   tags  = (const int*)d_in[1];
    const void*  mask  = d_in[2];
    const float* trans = (const float*)d_in[3];
    const float* start = (const float*)d_in[4];
    const float* endt  = (const float*)d_in[5];
    float* ws  = (float*)d_ws;
    float* out = (float*)d_out;

    crf_fwd  <<<BB / 2, 64, 0, stream>>>(em, tags, mask, trans, start, endt, ws);
    crf_final<<<1,      256, 0, stream>>>(ws, out);
}